// Round 16
// baseline (4875.676 us; speedup 1.0000x reference)
//
#include <hip/hip_runtime.h>

static constexpr int Bc = 128;   // batch
static constexpr int Tc = 256;   // timesteps
static constexpr int Ec = 512;   // input embed
static constexpr int Hc = 1024;  // hidden
static constexpr int SLOT = Bc * Hc;  // one h-state tile (elems)
// chunked h-state layout: [slot][chunk(128)][row(128)][col(8)] bf16
// elem addr (ushorts, within slot) = chunk*1024 + row*8 + col ; chunk = globalcol>>3

using bf16x8 = __attribute__((ext_vector_type(8))) short;
using f32x4  = __attribute__((ext_vector_type(4))) float;

__device__ __forceinline__ unsigned short f2bf(float f) {
  unsigned int u = __float_as_uint(f);
  u += 0x7FFFu + ((u >> 16) & 1u);
  return (unsigned short)(u >> 16);
}
__device__ __forceinline__ float sigm(float x) { return 1.0f / (1.0f + __expf(-x)); }
__device__ __forceinline__ float ftanh(float x) { return 1.0f - 2.0f / (__expf(2.0f * x) + 1.0f); }

#define MFMA16(A, Bf, C) __builtin_amdgcn_mfma_f32_16x16x32_bf16((A), (Bf), (C), 0, 0, 0)

// ---- global sync primitives ----
__device__ __forceinline__ void poll_rlx(const int* p, int tgt) {      // free-path (sleepy)
  while (__hip_atomic_load(p, __ATOMIC_RELAXED, __HIP_MEMORY_SCOPE_AGENT) < tgt)
    __builtin_amdgcn_s_sleep(1);
}
__device__ __forceinline__ void poll_fast(const int* p, int tgt) {     // critical-path
  while (__hip_atomic_load(p, __ATOMIC_RELAXED, __HIP_MEMORY_SCOPE_AGENT) < tgt) {}
}
__device__ __forceinline__ void sig(int* p, int v) {
  __hip_atomic_store(p, v, __ATOMIC_RELAXED, __HIP_MEMORY_SCOPE_AGENT);
}
__device__ __forceinline__ void stg_c(unsigned short* p, unsigned short v) {
  __hip_atomic_store(p, v, __ATOMIC_RELAXED, __HIP_MEMORY_SCOPE_AGENT);
}
// L3-coherent 16B load (sc1, bypasses possibly-stale L2) — ONLY for the h2c ring
__device__ __forceinline__ bf16x8 ldg_c(const unsigned short* p) {
  union { unsigned long long u[2]; bf16x8 v; } r;
  r.u[0] = __hip_atomic_load((const unsigned long long*)p,       __ATOMIC_RELAXED, __HIP_MEMORY_SCOPE_AGENT);
  r.u[1] = __hip_atomic_load((const unsigned long long*)(p + 4), __ATOMIC_RELAXED, __HIP_MEMORY_SCOPE_AGENT);
  return r.v;
}
// ---- LDS (workgroup-scope) flag primitives ----
__device__ __forceinline__ int lds_acq(const int* p) {
  return __hip_atomic_load(p, __ATOMIC_ACQUIRE, __HIP_MEMORY_SCOPE_WORKGROUP);
}
__device__ __forceinline__ void lds_rel(int* p, int v) {
  __hip_atomic_store(p, v, __ATOMIC_RELEASE, __HIP_MEMORY_SCOPE_WORKGROUP);
}

// ----------------- prep kernels (unchanged) -----------------
__global__ void k_cvt_bf16(const float* __restrict__ src, unsigned short* __restrict__ dst, int n) {
  int i = (blockIdx.x * blockDim.x + threadIdx.x) * 4;
  if (i + 3 < n) {
    f32x4 v = *(const f32x4*)(src + i);
    *(ushort4*)(dst + i) = make_ushort4(f2bf(v[0]), f2bf(v[1]), f2bf(v[2]), f2bf(v[3]));
  }
}

__global__ void k_prep_small(const float* __restrict__ bih0, const float* __restrict__ bhh0,
                             float* __restrict__ b0s,
                             unsigned short* __restrict__ h2c,     // [4][SLOT]
                             int* __restrict__ f1, int* __restrict__ f2) {
  int i = blockIdx.x * blockDim.x + threadIdx.x;  // grid covers 4*SLOT = 524288
  if (i < 4096) b0s[i] = bih0[i] + bhh0[i];
  h2c[i] = 0;
  if (i < 128 * 16) { f1[i] = 0; f2[i] = 0; }
}

// ----------------- layer-0 bulk GEMM (unchanged) -----------------
__global__ __launch_bounds__(512, 1) void k_l0(
    const unsigned short* __restrict__ xb, const unsigned short* __restrict__ W0,
    const float* __restrict__ b0s, unsigned short* __restrict__ H0)
{
  const int tid = threadIdx.x;
  const int lane = tid & 63, wid = tid >> 6;
  const int wM = wid >> 2, wN = wid & 3;           // 8 waves: 2(M) x 4(N)
  const int rowbase = blockIdx.x * 32 + wM * 16;
  const int jbase   = blockIdx.y * 64 + wN * 16;
  const int ri = lane & 15, kg = lane >> 4;

  const int r = rowbase + ri;
  const int t = r >> 7, b = r & (Bc - 1);
  const unsigned short* arow = xb + ((size_t)b * Tc + t) * Ec + kg * 8;

  const unsigned short* w0r = W0 + ((size_t)(0 * Hc + jbase + ri)) * Ec + kg * 8;
  const unsigned short* w2r = W0 + ((size_t)(2 * Hc + jbase + ri)) * Ec + kg * 8;
  const unsigned short* w3r = W0 + ((size_t)(3 * Hc + jbase + ri)) * Ec + kg * 8;

  f32x4 ai = {0,0,0,0}, ag = {0,0,0,0}, ao = {0,0,0,0};
#pragma unroll
  for (int kk = 0; kk < Ec / 32; ++kk) {
    bf16x8 a = *(const bf16x8*)(arow + kk * 32);
    ai = MFMA16(a, *(const bf16x8*)(w0r + kk * 32), ai);
    ag = MFMA16(a, *(const bf16x8*)(w2r + kk * 32), ag);
    ao = MFMA16(a, *(const bf16x8*)(w3r + kk * 32), ao);
  }
  const int j = jbase + ri;
  const float bi = b0s[j], bg = b0s[2 * Hc + j], bo = b0s[3 * Hc + j];
#pragma unroll
  for (int q = 0; q < 4; ++q) {
    const int rr = rowbase + kg * 4 + q;
    float c = sigm(ai[q] + bi) * ftanh(ag[q] + bg);
    float h = sigm(ao[q] + bo) * ftanh(c);
    H0[(size_t)(rr >> 7) * SLOT + (size_t)(j >> 3) * 1024 + (size_t)(rr & 127) * 8 + (j & 7)] = f2bf(h);
  }
}

// ----------------- recurrent kernel: decoupled waves + fence-free + split join ----------
// 256 WGs x 512 thr (8 waves), 1 WG/CU, PLAIN launch. WGs 0..127: layer1; 128..255:
// layer2. Free waves 0-3: next-step free half -> pbuf (sF/sG LDS stamps). Gated waves
// 4-7: poll own 32 producer slots -> stamp pollD[m] -> PHASE A (spin stamps 0,1; MFMA
// chunks 0-63) -> PHASE B (spin stamps 2,3; MFMA chunks 64-127) -> cell -> store ->
// vmcnt drain -> doneS; wave 4 aggregates + signals. NO per-step fence: h2c ring read
// via sc1 ldg_c (L3-coherent), everything else keeps warm L1/L2 (write-once/determinism).
__global__ __launch_bounds__(512, 1) void k_rec(
    const unsigned short* H0,                        // [256][SLOT] chunked (ws)
    const float* __restrict__ Wih, const float* __restrict__ Whh,  // [2][4096][1024] f32
    const float* __restrict__ bih, const float* __restrict__ bhh,  // [2][4096] f32
    unsigned short* h1c,                             // [Tc][SLOT] chunked (d_out upper half)
    unsigned short* h2c,                             // [4][SLOT] chunked (ws)
    int* f1, int* f2,                                // [128] slots x 16 ints (64B stride)
    float* out)                                      // [Tc][Bc][Hc] f32 (d_out)
{
  __shared__ unsigned short Wlds[2 * 64 * 64 * 8];   // 128 KiB: [tile][kstep][lane][8]
  __shared__ float pbuf[4][4][64][4];                // 16 KiB: [m][acc][lane][4] partials
  __shared__ int flg[32];                            // sF[0:4] sG[4:8] pollD[8:12]
                                                     // pollF[12:16] doneS[16:20]
  int* sF_   = flg + 0;
  int* sG_   = flg + 4;
  int* pollD = flg + 8;
  int* pollF = flg + 12;
  int* doneS = flg + 16;

  const int tid = threadIdx.x;
  const int lane = tid & 63, wid = tid >> 6;         // 8 waves
  const int m = wid & 3;                             // M-pair index within role group
  const bool gatedw = (wid >= 4);
  const int bid = blockIdx.x;
  const int layer = bid >> 7;
  const int w = bid & 127;
  const int j0 = w * 8;
  const int ri = lane & 15, kg = lane >> 4;

  if (tid < 32) flg[tid] = 0;

  // ---- prologue: weights fp32 -> bf16 into LDS, fragment-major (stride 512) ----
  const size_t lw = (size_t)layer * 4096 * 1024;
  for (int s = tid; s < 2 * 64 * 64; s += 512) {
    const int l   = s & 63;
    const int kkg = (s >> 6) & 63;
    const int t   = s >> 12;
    const int rr  = l & 15;
    const int gate = t * 2 + (rr >> 3);
    const int R = gate * 1024 + j0 + (rr & 7);
    const int k = kkg * 32 + (l >> 4) * 8;
    const float* src = (k < 1024) ? (Wih + lw + (size_t)R * 1024 + k)
                                  : (Whh + lw + (size_t)R * 1024 + (k - 1024));
    f32x4 v0 = *(const f32x4*)src;
    f32x4 v1 = *(const f32x4*)(src + 4);
    ushort4* d = (ushort4*)(Wlds + (size_t)s * 8);
    d[0] = make_ushort4(f2bf(v0[0]), f2bf(v0[1]), f2bf(v0[2]), f2bf(v0[3]));
    d[1] = make_ushort4(f2bf(v1[0]), f2bf(v1[1]), f2bf(v1[2]), f2bf(v1[3]));
  }

  const int jme = j0 + (ri & 7);
  const int g0 = (ri < 8) ? 0 : 1;                  // tile0: i | f
  const int g1 = (ri < 8) ? 2 : 3;                  // tile1: g | o
  const float bias0 = bih[layer * 4096 + g0 * 1024 + jme] + bhh[layer * 4096 + g0 * 1024 + jme];
  const float bias1 = bih[layer * 4096 + g1 * 1024 + jme] + bhh[layer * 4096 + g1 * 1024 + jme];

  float c0[4]  = {0.f, 0.f, 0.f, 0.f};              // c-state (gated waves)
  float c1s[4] = {0.f, 0.f, 0.f, 0.f};

  const unsigned short* lds0 = Wlds + (size_t)lane * 8;
  const unsigned short* lds1 = Wlds + (size_t)64 * 64 * 8 + (size_t)lane * 8;
  const int abase = kg * 1024 + (m * 32 + ri) * 8;  // chunked A base (rows m*32+ri, +16)
  const bool lo = (ri < 8);

  f32x4 acc00, acc01, acc10, acc11;
#define ZERO4() { acc00 = (f32x4){0,0,0,0}; acc01 = (f32x4){0,0,0,0}; \
                  acc10 = (f32x4){0,0,0,0}; acc11 = (f32x4){0,0,0,0}; }
#define PLOAD()  { acc00 = *(const f32x4*)&pbuf[m][0][lane][0]; \
                   acc01 = *(const f32x4*)&pbuf[m][1][lane][0]; \
                   acc10 = *(const f32x4*)&pbuf[m][2][lane][0]; \
                   acc11 = *(const f32x4*)&pbuf[m][3][lane][0]; }
#define PWRITE() { *(f32x4*)&pbuf[m][0][lane][0] = acc00; \
                   *(f32x4*)&pbuf[m][1][lane][0] = acc01; \
                   *(f32x4*)&pbuf[m][2][lane][0] = acc10; \
                   *(f32x4*)&pbuf[m][3][lane][0] = acc11; }

// plain cached loads, kk in [K0,K1)
#define HALF_MM4R(Abase, LDSOFF, K0, K1)                                    \
  {                                                                         \
    const unsigned short* ap_ = (Abase) + abase;                            \
    _Pragma("unroll")                                                       \
    for (int kk = (K0); kk < (K1); ++kk) {                                  \
      bf16x8 b0 = *(const bf16x8*)(lds0 + (LDSOFF) + kk * 512);             \
      bf16x8 b1 = *(const bf16x8*)(lds1 + (LDSOFF) + kk * 512);             \
      bf16x8 vlo = *(const bf16x8*)(ap_ + kk * 4096);                       \
      bf16x8 vhi = *(const bf16x8*)(ap_ + kk * 4096 + 128);                 \
      acc00 = MFMA16(vlo, b0, acc00);                                       \
      acc01 = MFMA16(vlo, b1, acc01);                                       \
      acc10 = MFMA16(vhi, b0, acc10);                                       \
      acc11 = MFMA16(vhi, b1, acc11);                                       \
    }                                                                       \
  }

// sc1 L3-coherent loads (h2c ring only), kk in [K0,K1)
#define HALF_MM4C(Abase, LDSOFF, K0, K1)                                    \
  {                                                                         \
    const unsigned short* ap_ = (Abase) + abase;                            \
    _Pragma("unroll")                                                       \
    for (int kk = (K0); kk < (K1); ++kk) {                                  \
      bf16x8 b0 = *(const bf16x8*)(lds0 + (LDSOFF) + kk * 512);             \
      bf16x8 b1 = *(const bf16x8*)(lds1 + (LDSOFF) + kk * 512);             \
      bf16x8 vlo = ldg_c(ap_ + kk * 4096);                                  \
      bf16x8 vhi = ldg_c(ap_ + kk * 4096 + 128);                            \
      acc00 = MFMA16(vlo, b0, acc00);                                       \
      acc01 = MFMA16(vlo, b1, acc01);                                       \
      acc10 = MFMA16(vhi, b0, acc10);                                       \
      acc11 = MFMA16(vhi, b1, acc11);                                       \
    }                                                                       \
  }

#define CELL4(accA, accB, cre, hnarr)                                       \
  _Pragma("unroll")                                                         \
  for (int q = 0; q < 4; ++q) {                                             \
    float x0 = accA[q] + bias0;                                             \
    float x1 = accB[q] + bias1;                                             \
    float p0 = __shfl_xor(x0, 8);                                           \
    float p1 = __shfl_xor(x1, 8);                                           \
    float gi = lo ? x0 : p0;                                                \
    float gf = lo ? p0 : x0;                                                \
    float gg = lo ? x1 : p1;                                                \
    float go = lo ? p1 : x1;                                                \
    float cn = sigm(gf) * cre[q] + sigm(gi) * ftanh(gg);                    \
    hnarr[q] = sigm(go) * ftanh(cn);                                        \
    cre[q] = cn;                                                            \
  }

// free-wave join (sleepy): poll own 32 slots, stamp, spin all four
#define GPOLL_BAR(farr, tgt, stamp)                                         \
  { if (lane < 32) poll_rlx((farr) + (m * 32 + lane) * 16, (tgt));          \
    if (lane == 0) lds_rel(&(stamp)[m], (tgt));                             \
    while (lds_acq(&(stamp)[0]) < (tgt) || lds_acq(&(stamp)[1]) < (tgt) ||  \
           lds_acq(&(stamp)[2]) < (tgt) || lds_acq(&(stamp)[3]) < (tgt)) {} }

  __syncthreads();                                  // Wlds + flags ready (only WG barrier)

  if (layer == 0) {
    if (!gatedw) {
      // ---------- layer-1 FREE wave m: produce partial(t) = H0(t) half ----------
      ZERO4() HALF_MM4R(H0, 0, 0, 32)               // partial(0)
      for (int t = 0; t < Tc; ++t) {
        while (lds_acq(&sG_[m]) < t) {}             // slot free (gated consumed t-1)
        PWRITE()
        if (lane == 0) lds_rel(&sF_[m], t + 1);     // partial(t) published
        if (t + 1 < Tc) { ZERO4() HALF_MM4R(H0 + (size_t)(t + 1) * SLOT, 0, 0, 32) }
      }
    } else {
      // ---------- layer-1 GATED wave m: critical chain, split join ----------
      for (int p = 0; p < Tc; ++p) {
        if (p >= 1) {
          if (lane < 32) poll_fast(f1 + (m * 32 + lane) * 16, p);
          if (lane == 0) lds_rel(&pollD[m], p);
        }
        while (lds_acq(&sF_[m]) < p + 1) {}         // partial(p) ready
        PLOAD()
        if (lane == 0) lds_rel(&sG_[m], p + 1);     // slot consumed
        if (p >= 1) {
          const unsigned short* gb = h1c + (size_t)(p - 1) * SLOT;
          while (lds_acq(&pollD[0]) < p || lds_acq(&pollD[1]) < p) {}
          HALF_MM4R(gb, 32 * 512, 0, 16)            // chunks 0-63 (producers 0-63)
          while (lds_acq(&pollD[2]) < p || lds_acq(&pollD[3]) < p) {}
          HALF_MM4R(gb, 32 * 512, 16, 32)           // chunks 64-127
        }
        float hn0[4], hn1[4];
        CELL4(acc00, acc01, c0, hn0)
        CELL4(acc10, acc11, c1s, hn1)
        if (lo) {
          unsigned short* hb = h1c + (size_t)p * SLOT + (size_t)w * 1024 + (ri & 7);
#pragma unroll
          for (int q = 0; q < 4; ++q) {
            const int r0 = m * 32 + kg * 4 + q;
            stg_c(hb + (size_t)r0 * 8, f2bf(hn0[q]));
            stg_c(hb + (size_t)(r0 + 16) * 8, f2bf(hn1[q]));
          }
        }
        __asm__ volatile("s_waitcnt vmcnt(0)" ::: "memory");  // stores ACKed at L3
        if (lane == 0) lds_rel(&doneS[m], p + 1);
        if (m == 0) {
          while (lds_acq(&doneS[1]) < p + 1 || lds_acq(&doneS[2]) < p + 1 ||
                 lds_acq(&doneS[3]) < p + 1) {}
          if (lane == 0) sig(f1 + w * 16, p + 1);
        }
      }
    }
  } else {
    if (!gatedw) {
      // ---------- layer-2 FREE wave m: produce cross(t) = h1(t) half ----------
      GPOLL_BAR(f1, 1, pollF)                       // h1(0) ready
      ZERO4() HALF_MM4R(h1c, 0, 0, 32)              // cross(0)
      for (int t = 0; t < Tc; ++t) {
        while (lds_acq(&sG_[m]) < t) {}
        PWRITE()
        if (lane == 0) lds_rel(&sF_[m], t + 1);
        if (t + 1 < Tc) {
          GPOLL_BAR(f1, t + 2, pollF)               // h1(t+1) ready everywhere
          ZERO4() HALF_MM4R(h1c + (size_t)(t + 1) * SLOT, 0, 0, 32)
        }
      }
    } else {
      // ---------- layer-2 GATED wave m: critical chain, split join, sc1 ring ----------
      for (int s = 0; s < Tc; ++s) {
        if (s >= 1) {
          if (lane < 32) poll_fast(f2 + (m * 32 + lane) * 16, s);
          if (lane == 0) lds_rel(&pollD[m], s);
        }
        while (lds_acq(&sF_[m]) < s + 1) {}         // cross(s) ready
        PLOAD()
        if (lane == 0) lds_rel(&sG_[m], s + 1);
        {
          const unsigned short* gb = h2c + (size_t)((s - 1) & 3) * SLOT;  // s=0: zeros
          if (s >= 1) { while (lds_acq(&pollD[0]) < s || lds_acq(&pollD[1]) < s) {} }
          HALF_MM4C(gb, 32 * 512, 0, 16)            // chunks 0-63
          if (s >= 1) { while (lds_acq(&pollD[2]) < s || lds_acq(&pollD[3]) < s) {} }
          HALF_MM4C(gb, 32 * 512, 16, 32)           // chunks 64-127
        }
        float hn0[4], hn1[4];
        CELL4(acc00, acc01, c0, hn0)
        CELL4(acc10, acc11, c1s, hn1)
        if (lo) {
          unsigned short* hb = h2c + (size_t)(s & 3) * SLOT + (size_t)w * 1024 + (ri & 7);
#pragma unroll
          for (int q = 0; q < 4; ++q) {
            const int r0 = m * 32 + kg * 4 + q;
            stg_c(hb + (size_t)r0 * 8, f2bf(hn0[q]));
            stg_c(hb + (size_t)(r0 + 16) * 8, f2bf(hn1[q]));
          }
        }
        __asm__ volatile("s_waitcnt vmcnt(0)" ::: "memory");
        if (lane == 0) lds_rel(&doneS[m], s + 1);
        if (m == 0) {
          while (lds_acq(&doneS[1]) < s + 1 || lds_acq(&doneS[2]) < s + 1 ||
                 lds_acq(&doneS[3]) < s + 1) {}
          if (lane == 0) sig(f2 + w * 16, s + 1);
        }
        // out stores off-chain (alias ordering inherited from f1/f2 waits)
        if (lo) {
          float* po = out + (size_t)s * SLOT;
#pragma unroll
          for (int q = 0; q < 4; ++q) {
            const int r0 = m * 32 + kg * 4 + q;
            po[(size_t)r0 * Hc + jme] = hn0[q];
            po[(size_t)(r0 + 16) * Hc + jme] = hn1[q];
          }
        }
      }
    }
  }
}

// ----------------- launcher -----------------
extern "C" void kernel_launch(void* const* d_in, const int* in_sizes, int n_in,
                              void* d_out, int out_size, void* d_ws, size_t ws_size,
                              hipStream_t stream) {
  const float* x     = (const float*)d_in[0];
  const float* W_ih0 = (const float*)d_in[1];
  // d_in[2] = W_hh0 (unused: layer-0 state is always zero)
  const float* b_ih0 = (const float*)d_in[3];
  const float* b_hh0 = (const float*)d_in[4];
  const float* W_ihr = (const float*)d_in[5];
  const float* W_hhr = (const float*)d_in[6];
  const float* b_ihr = (const float*)d_in[7];
  const float* b_hhr = (const float*)d_in[8];

  // ws layout (~65 MB): H0 64MB + h2c 1MB + flags + b0s
  char* ws = (char*)d_ws;
  constexpr size_t H0_OFF  = 0;                                   // 256*SLOT bf16 = 64 MB
  constexpr size_t H2B_OFF = H0_OFF + (size_t)Tc * SLOT * 2;      // 4*SLOT bf16 = 1 MB
  constexpr size_t F1_OFF  = H2B_OFF + (size_t)4 * SLOT * 2;      // 8 KB
  constexpr size_t F2_OFF  = F1_OFF + 128 * 16 * 4;               // 8 KB

  unsigned short* H0  = (unsigned short*)(ws + H0_OFF);
  unsigned short* h2c = (unsigned short*)(ws + H2B_OFF);
  float* b0s = (float*)(ws + F2_OFF + 128 * 16 * 4);              // 16 KB, after flags
  int* f1 = (int*)(ws + F1_OFF);
  int* f2 = (int*)(ws + F2_OFF);

  // d_out layout during compute (same byte ranges as rounds 8-15; alias proofs carry):
  //   lower half transient: xb (32MB @0) + W0b (4MB @32MB), read only by k_l0.
  //   upper half: h1c [Tc][SLOT] bf16 write-once slots; out[s] (s>=128) overwrites
  //   h1 slots {2s-256, 2s-255} only after the f1/f2 waits order it past all readers.
  unsigned short* xb  = (unsigned short*)d_out;
  unsigned short* W0b = (unsigned short*)d_out + (size_t)Bc * Tc * Ec;
  unsigned short* h1c = (unsigned short*)d_out + (size_t)Tc * SLOT;
  float* out = (float*)d_out;

  int n0 = 4096 * 512;
  k_cvt_bf16<<<n0 / 1024, 256, 0, stream>>>(W_ih0, W0b, n0);
  int nx = Bc * Tc * Ec;
  k_cvt_bf16<<<nx / 1024, 256, 0, stream>>>(x, xb, nx);
  k_prep_small<<<2048, 256, 0, stream>>>(b_ih0, b_hh0, b0s, h2c, f1, f2);
  k_l0<<<dim3(1024, 16), 512, 0, stream>>>(xb, W0b, b0s, H0);

  // PLAIN launch; co-residency structural (~144KB LDS -> 1 WG/CU, grid = 256 = #CUs).
  k_rec<<<dim3(256), dim3(512), 0, stream>>>(H0, W_ihr, W_hhr, b_ihr, b_hhr,
                                             h1c, h2c, f1, f2, out);
}

// Round 17
// 4143.070 us; speedup vs baseline: 1.1768x; 1.1768x over previous
//
#include <hip/hip_runtime.h>

static constexpr int Bc = 128;   // batch
static constexpr int Tc = 256;   // timesteps
static constexpr int Ec = 512;   // input embed
static constexpr int Hc = 1024;  // hidden
static constexpr int SLOT = Bc * Hc;  // one h-state tile (elems)
// chunked h-state layout: [slot][chunk(128)][row(128)][col(8)] bf16
// elem addr (ushorts, within slot) = chunk*1024 + row*8 + col ; chunk = globalcol>>3

using bf16x8 = __attribute__((ext_vector_type(8))) short;
using f32x4  = __attribute__((ext_vector_type(4))) float;

__device__ __forceinline__ unsigned short f2bf(float f) {
  unsigned int u = __float_as_uint(f);
  u += 0x7FFFu + ((u >> 16) & 1u);
  return (unsigned short)(u >> 16);
}
__device__ __forceinline__ float sigm(float x) { return 1.0f / (1.0f + __expf(-x)); }
__device__ __forceinline__ float ftanh(float x) { return 1.0f - 2.0f / (__expf(2.0f * x) + 1.0f); }

#define MFMA16(A, Bf, C) __builtin_amdgcn_mfma_f32_16x16x32_bf16((A), (Bf), (C), 0, 0, 0)

// ---- global sync primitives: r15-proven ----
__device__ __forceinline__ void poll_rlx(const int* p, int tgt) {
  while (__hip_atomic_load(p, __ATOMIC_RELAXED, __HIP_MEMORY_SCOPE_AGENT) < tgt)
    __builtin_amdgcn_s_sleep(1);
}
__device__ __forceinline__ void sig(int* p, int v) {
  __hip_atomic_store(p, v, __ATOMIC_RELAXED, __HIP_MEMORY_SCOPE_AGENT);
}
__device__ __forceinline__ void stg_c(unsigned short* p, unsigned short v) {
  __hip_atomic_store(p, v, __ATOMIC_RELAXED, __HIP_MEMORY_SCOPE_AGENT);
}
// ---- LDS (workgroup-scope) flag primitives ----
__device__ __forceinline__ int lds_acq(const int* p) {
  return __hip_atomic_load(p, __ATOMIC_ACQUIRE, __HIP_MEMORY_SCOPE_WORKGROUP);
}
__device__ __forceinline__ void lds_rel(int* p, int v) {
  __hip_atomic_store(p, v, __ATOMIC_RELEASE, __HIP_MEMORY_SCOPE_WORKGROUP);
}

// ----------------- prep kernels (unchanged) -----------------
__global__ void k_cvt_bf16(const float* __restrict__ src, unsigned short* __restrict__ dst, int n) {
  int i = (blockIdx.x * blockDim.x + threadIdx.x) * 4;
  if (i + 3 < n) {
    f32x4 v = *(const f32x4*)(src + i);
    *(ushort4*)(dst + i) = make_ushort4(f2bf(v[0]), f2bf(v[1]), f2bf(v[2]), f2bf(v[3]));
  }
}

__global__ void k_prep_small(const float* __restrict__ bih0, const float* __restrict__ bhh0,
                             float* __restrict__ b0s,
                             unsigned short* __restrict__ h2c,     // [4][SLOT]
                             int* __restrict__ f1, int* __restrict__ f2) {
  int i = blockIdx.x * blockDim.x + threadIdx.x;  // grid covers 4*SLOT = 524288
  if (i < 4096) b0s[i] = bih0[i] + bhh0[i];
  h2c[i] = 0;
  if (i < 128 * 16) { f1[i] = 0; f2[i] = 0; }
}

// ----------------- layer-0 bulk GEMM: NEW traffic-minimal version -----------------
// Block = one timestep t = blockIdx.x (128 batch rows) x 64 hidden (blockIdx.y).
// xb tile [128 rows][512 K] staged in LDS once (128 KB, chunk-XOR swizzled);
// 4 waves, each owns a j-16 slice and amortizes every W-fragment load across
// 8 M-subtiles (16 rows each) -> W read once per block, A read once per block.
// Output H0 in the CHUNKED layout (slot = t).
__global__ __launch_bounds__(256, 1) void k_l0(
    const unsigned short* __restrict__ xb, const unsigned short* __restrict__ W0,
    const float* __restrict__ b0s, unsigned short* __restrict__ H0)
{
  __shared__ unsigned short Axs[64 * 128 * 8];     // 128 KiB: [chunk(64)][row^swz(128)][8]
  const int tid = threadIdx.x;
  const int lane = tid & 63, wid = tid >> 6;       // 4 waves
  const int bx = blockIdx.x;                       // timestep t
  const int jbase = blockIdx.y * 64 + wid * 16;    // this wave's j-16 slice
  const int ri = lane & 15, kg = lane >> 4;

  // ---- stage xb[t] tile: row = batch b, chunk = k>>3; swizzle row ^ (chunk&15) ----
  for (int i = tid; i < 8192; i += 256) {
    const int row = i >> 6;                        // 0..127 (= batch b)
    const int chunk = i & 63;                      // 0..63  (k = chunk*8)
    const int phys = chunk * 128 + (row ^ (chunk & 15));
    *(bf16x8*)(Axs + (size_t)phys * 8) =
        *(const bf16x8*)(xb + ((size_t)row * Tc + bx) * Ec + chunk * 8);
  }
  __syncthreads();

  const int j = jbase + ri;
  const float bi = b0s[j], bg = b0s[2 * Hc + j], bo = b0s[3 * Hc + j];
  const unsigned short* w0r = W0 + ((size_t)(0 * Hc + j)) * Ec + kg * 8;
  const unsigned short* w2r = W0 + ((size_t)(2 * Hc + j)) * Ec + kg * 8;
  const unsigned short* w3r = W0 + ((size_t)(3 * Hc + j)) * Ec + kg * 8;

  f32x4 ai[8], ag[8], ao[8];
#pragma unroll
  for (int u = 0; u < 8; ++u) { ai[u] = (f32x4){0,0,0,0}; ag[u] = (f32x4){0,0,0,0}; ao[u] = (f32x4){0,0,0,0}; }

#pragma unroll 4
  for (int kk = 0; kk < Ec / 32; ++kk) {
    bf16x8 wi = *(const bf16x8*)(w0r + kk * 32);
    bf16x8 wg = *(const bf16x8*)(w2r + kk * 32);
    bf16x8 wo = *(const bf16x8*)(w3r + kk * 32);
    const int ch = kk * 4 + kg;
#pragma unroll
    for (int u = 0; u < 8; ++u) {
      const int phys = ch * 128 + ((u * 16 + ri) ^ (ch & 15));
      bf16x8 a = *(const bf16x8*)(Axs + (size_t)phys * 8);
      ai[u] = MFMA16(a, wi, ai[u]);
      ag[u] = MFMA16(a, wg, ag[u]);
      ao[u] = MFMA16(a, wo, ao[u]);
    }
  }

  // epilogue: H0 chunked store, slot = t = bx, row-in-slot = batch b
  unsigned short* hb = H0 + (size_t)bx * SLOT + (size_t)(j >> 3) * 1024 + (j & 7);
#pragma unroll
  for (int u = 0; u < 8; ++u) {
#pragma unroll
    for (int q = 0; q < 4; ++q) {
      const int b = u * 16 + kg * 4 + q;           // batch row (C layout: (lane>>4)*4+reg)
      float c = sigm(ai[u][q] + bi) * ftanh(ag[u][q] + bg);
      float h = sigm(ao[u][q] + bo) * ftanh(c);
      hb[(size_t)b * 8] = f2bf(h);
    }
  }
}

// ----------------- recurrent kernel: r15 verbatim (best measured: 4.02 ms) ------------------
// 256 WGs x 512 thr (8 waves), 1 WG/CU (~144KB LDS), PLAIN launch.
// WGs 0..127: layer1; 128..255: layer2. Free waves 0-3 compute the dependency-free half
// of the NEXT step in registers and hand it to gated wave m via pbuf[m] guarded by LDS
// stamps sF/sG. Gated waves 4-7 run the critical chain only: poll global flags (32
// slots each, pollD LDS barrier) -> PLOAD -> gated half -> cell -> store -> vmcnt
// drain -> doneS stamp; wave 4 aggregates doneS and signals.
__global__ __launch_bounds__(512, 1) void k_rec(
    const unsigned short* H0,                        // [256][SLOT] chunked (ws)
    const float* __restrict__ Wih, const float* __restrict__ Whh,  // [2][4096][1024] f32
    const float* __restrict__ bih, const float* __restrict__ bhh,  // [2][4096] f32
    unsigned short* h1c,                             // [Tc][SLOT] chunked (d_out upper half)
    unsigned short* h2c,                             // [4][SLOT] chunked (ws)
    int* f1, int* f2,                                // [128] slots x 16 ints (64B stride)
    float* out)                                      // [Tc][Bc][Hc] f32 (d_out)
{
  __shared__ unsigned short Wlds[2 * 64 * 64 * 8];   // 128 KiB: [tile][kstep][lane][8]
  __shared__ float pbuf[4][4][64][4];                // 16 KiB: [m][acc][lane][4] partials
  __shared__ int flg[32];                            // sF[0:4] sG[4:8] pollD[8:12]
                                                     // pollF[12:16] doneS[16:20]
  int* sF_   = flg + 0;
  int* sG_   = flg + 4;
  int* pollD = flg + 8;
  int* pollF = flg + 12;
  int* doneS = flg + 16;

  const int tid = threadIdx.x;
  const int lane = tid & 63, wid = tid >> 6;         // 8 waves
  const int m = wid & 3;                             // M-pair index within role group
  const bool gatedw = (wid >= 4);
  const int bid = blockIdx.x;
  const int layer = bid >> 7;
  const int w = bid & 127;
  const int j0 = w * 8;
  const int ri = lane & 15, kg = lane >> 4;

  if (tid < 32) flg[tid] = 0;

  // ---- prologue: weights fp32 -> bf16 into LDS, fragment-major (stride 512) ----
  const size_t lw = (size_t)layer * 4096 * 1024;
  for (int s = tid; s < 2 * 64 * 64; s += 512) {
    const int l   = s & 63;
    const int kkg = (s >> 6) & 63;
    const int t   = s >> 12;
    const int rr  = l & 15;
    const int gate = t * 2 + (rr >> 3);
    const int R = gate * 1024 + j0 + (rr & 7);
    const int k = kkg * 32 + (l >> 4) * 8;
    const float* src = (k < 1024) ? (Wih + lw + (size_t)R * 1024 + k)
                                  : (Whh + lw + (size_t)R * 1024 + (k - 1024));
    f32x4 v0 = *(const f32x4*)src;
    f32x4 v1 = *(const f32x4*)(src + 4);
    ushort4* d = (ushort4*)(Wlds + (size_t)s * 8);
    d[0] = make_ushort4(f2bf(v0[0]), f2bf(v0[1]), f2bf(v0[2]), f2bf(v0[3]));
    d[1] = make_ushort4(f2bf(v1[0]), f2bf(v1[1]), f2bf(v1[2]), f2bf(v1[3]));
  }

  const int jme = j0 + (ri & 7);
  const int g0 = (ri < 8) ? 0 : 1;                  // tile0: i | f
  const int g1 = (ri < 8) ? 2 : 3;                  // tile1: g | o
  const float bias0 = bih[layer * 4096 + g0 * 1024 + jme] + bhh[layer * 4096 + g0 * 1024 + jme];
  const float bias1 = bih[layer * 4096 + g1 * 1024 + jme] + bhh[layer * 4096 + g1 * 1024 + jme];

  float c0[4]  = {0.f, 0.f, 0.f, 0.f};              // c-state (gated waves)
  float c1s[4] = {0.f, 0.f, 0.f, 0.f};

  const unsigned short* lds0 = Wlds + (size_t)lane * 8;
  const unsigned short* lds1 = Wlds + (size_t)64 * 64 * 8 + (size_t)lane * 8;
  const int abase = kg * 1024 + (m * 32 + ri) * 8;  // chunked A base (rows m*32+ri, +16)
  const bool lo = (ri < 8);

  f32x4 acc00, acc01, acc10, acc11;
#define ZERO4() { acc00 = (f32x4){0,0,0,0}; acc01 = (f32x4){0,0,0,0}; \
                  acc10 = (f32x4){0,0,0,0}; acc11 = (f32x4){0,0,0,0}; }
#define PLOAD()  { acc00 = *(const f32x4*)&pbuf[m][0][lane][0]; \
                   acc01 = *(const f32x4*)&pbuf[m][1][lane][0]; \
                   acc10 = *(const f32x4*)&pbuf[m][2][lane][0]; \
                   acc11 = *(const f32x4*)&pbuf[m][3][lane][0]; }
#define PWRITE() { *(f32x4*)&pbuf[m][0][lane][0] = acc00; \
                   *(f32x4*)&pbuf[m][1][lane][0] = acc01; \
                   *(f32x4*)&pbuf[m][2][lane][0] = acc10; \
                   *(f32x4*)&pbuf[m][3][lane][0] = acc11; }

#define HALF_MM4(Abase, LDSOFF)                                             \
  {                                                                         \
    const unsigned short* ap_ = (Abase) + abase;                            \
    _Pragma("unroll")                                                       \
    for (int kk = 0; kk < 32; ++kk) {                                       \
      bf16x8 b0 = *(const bf16x8*)(lds0 + (LDSOFF) + kk * 512);             \
      bf16x8 b1 = *(const bf16x8*)(lds1 + (LDSOFF) + kk * 512);             \
      bf16x8 vlo = *(const bf16x8*)(ap_ + kk * 4096);                       \
      bf16x8 vhi = *(const bf16x8*)(ap_ + kk * 4096 + 128);                 \
      acc00 = MFMA16(vlo, b0, acc00);                                       \
      acc01 = MFMA16(vlo, b1, acc01);                                       \
      acc10 = MFMA16(vhi, b0, acc10);                                       \
      acc11 = MFMA16(vhi, b1, acc11);                                       \
    }                                                                       \
  }

#define CELL4(accA, accB, cre, hnarr)                                       \
  _Pragma("unroll")                                                         \
  for (int q = 0; q < 4; ++q) {                                             \
    float x0 = accA[q] + bias0;                                             \
    float x1 = accB[q] + bias1;                                             \
    float p0 = __shfl_xor(x0, 8);                                           \
    float p1 = __shfl_xor(x1, 8);                                           \
    float gi = lo ? x0 : p0;                                                \
    float gf = lo ? p0 : x0;                                                \
    float gg = lo ? x1 : p1;                                                \
    float go = lo ? p1 : x1;                                                \
    float cn = sigm(gf) * cre[q] + sigm(gi) * ftanh(gg);                    \
    hnarr[q] = sigm(go) * ftanh(cn);                                        \
    cre[q] = cn;                                                            \
  }

#define GPOLL_BAR(farr, tgt, stamp)                                         \
  { if (lane < 32) poll_rlx((farr) + (m * 32 + lane) * 16, (tgt));          \
    if (lane == 0) lds_rel(&(stamp)[m], (tgt));                             \
    while (lds_acq(&(stamp)[0]) < (tgt) || lds_acq(&(stamp)[1]) < (tgt) ||  \
           lds_acq(&(stamp)[2]) < (tgt) || lds_acq(&(stamp)[3]) < (tgt)) {} }

  __syncthreads();                                  // Wlds + flags ready (only WG barrier)

  if (layer == 0) {
    if (!gatedw) {
      // ---------- layer-1 FREE wave m: produce partial(t) = H0(t) half ----------
      ZERO4() HALF_MM4(H0, 0)                       // partial(0)
      for (int t = 0; t < Tc; ++t) {
        while (lds_acq(&sG_[m]) < t) {}             // slot free (gated consumed t-1)
        PWRITE()
        if (lane == 0) lds_rel(&sF_[m], t + 1);     // partial(t) published
        if (t + 1 < Tc) { ZERO4() HALF_MM4(H0 + (size_t)(t + 1) * SLOT, 0) }
      }
    } else {
      // ---------- layer-1 GATED wave m: critical chain ----------
      for (int p = 0; p < Tc; ++p) {
        if (p >= 1) GPOLL_BAR(f1, p, pollD)         // h1(p-1) ready everywhere
        while (lds_acq(&sF_[m]) < p + 1) {}         // partial(p) ready
        PLOAD()
        if (lane == 0) lds_rel(&sG_[m], p + 1);     // slot consumed
        if (p >= 1) HALF_MM4(h1c + (size_t)(p - 1) * SLOT, 32 * 512)
        float hn0[4], hn1[4];
        CELL4(acc00, acc01, c0, hn0)
        CELL4(acc10, acc11, c1s, hn1)
        if (lo) {
          unsigned short* hb = h1c + (size_t)p * SLOT + (size_t)w * 1024 + (ri & 7);
#pragma unroll
          for (int q = 0; q < 4; ++q) {
            const int r0 = m * 32 + kg * 4 + q;
            stg_c(hb + (size_t)r0 * 8, f2bf(hn0[q]));
            stg_c(hb + (size_t)(r0 + 16) * 8, f2bf(hn1[q]));
          }
        }
        __asm__ volatile("s_waitcnt vmcnt(0)" ::: "memory");  // stores ACKed at L3
        if (lane == 0) lds_rel(&doneS[m], p + 1);
        if (m == 0) {
          while (lds_acq(&doneS[1]) < p + 1 || lds_acq(&doneS[2]) < p + 1 ||
                 lds_acq(&doneS[3]) < p + 1) {}
          if (lane == 0) sig(f1 + w * 16, p + 1);
        }
      }
    }
  } else {
    if (!gatedw) {
      // ---------- layer-2 FREE wave m: produce cross(t) = h1(t) half ----------
      GPOLL_BAR(f1, 1, pollF)                       // h1(0) ready
      ZERO4() HALF_MM4(h1c, 0)                      // cross(0)
      for (int t = 0; t < Tc; ++t) {
        while (lds_acq(&sG_[m]) < t) {}
        PWRITE()
        if (lane == 0) lds_rel(&sF_[m], t + 1);
        if (t + 1 < Tc) {
          GPOLL_BAR(f1, t + 2, pollF)               // h1(t+1) ready everywhere
          ZERO4() HALF_MM4(h1c + (size_t)(t + 1) * SLOT, 0)
        }
      }
    } else {
      // ---------- layer-2 GATED wave m: critical chain ----------
      for (int s = 0; s < Tc; ++s) {
        if (s >= 1) GPOLL_BAR(f2, s, pollD)         // h2(s-1) ready everywhere
        __builtin_amdgcn_fence(__ATOMIC_ACQUIRE, "agent");  // h2c ring staleness guard
        while (lds_acq(&sF_[m]) < s + 1) {}         // cross(s) ready
        PLOAD()
        if (lane == 0) lds_rel(&sG_[m], s + 1);
        HALF_MM4(h2c + (size_t)((s - 1) & 3) * SLOT, 32 * 512)  // s=0: slot 3 zeros
        float hn0[4], hn1[4];
        CELL4(acc00, acc01, c0, hn0)
        CELL4(acc10, acc11, c1s, hn1)
        if (lo) {
          unsigned short* hb = h2c + (size_t)(s & 3) * SLOT + (size_t)w * 1024 + (ri & 7);
#pragma unroll
          for (int q = 0; q < 4; ++q) {
            const int r0 = m * 32 + kg * 4 + q;
            stg_c(hb + (size_t)r0 * 8, f2bf(hn0[q]));
            stg_c(hb + (size_t)(r0 + 16) * 8, f2bf(hn1[q]));
          }
        }
        __asm__ volatile("s_waitcnt vmcnt(0)" ::: "memory");
        if (lane == 0) lds_rel(&doneS[m], s + 1);
        if (m == 0) {
          while (lds_acq(&doneS[1]) < s + 1 || lds_acq(&doneS[2]) < s + 1 ||
                 lds_acq(&doneS[3]) < s + 1) {}
          if (lane == 0) sig(f2 + w * 16, s + 1);
        }
        // out stores off-chain (alias ordering inherited from f1/f2 waits, re-audited)
        if (lo) {
          float* po = out + (size_t)s * SLOT;
#pragma unroll
          for (int q = 0; q < 4; ++q) {
            const int r0 = m * 32 + kg * 4 + q;
            po[(size_t)r0 * Hc + jme] = hn0[q];
            po[(size_t)(r0 + 16) * Hc + jme] = hn1[q];
          }
        }
      }
    }
  }
}

// ----------------- launcher -----------------
extern "C" void kernel_launch(void* const* d_in, const int* in_sizes, int n_in,
                              void* d_out, int out_size, void* d_ws, size_t ws_size,
                              hipStream_t stream) {
  const float* x     = (const float*)d_in[0];
  const float* W_ih0 = (const float*)d_in[1];
  // d_in[2] = W_hh0 (unused: layer-0 state is always zero)
  const float* b_ih0 = (const float*)d_in[3];
  const float* b_hh0 = (const float*)d_in[4];
  const float* W_ihr = (const float*)d_in[5];
  const float* W_hhr = (const float*)d_in[6];
  const float* b_ihr = (const float*)d_in[7];
  const float* b_hhr = (const float*)d_in[8];

  // ws layout (~65 MB): H0 64MB + h2c 1MB + flags + b0s
  char* ws = (char*)d_ws;
  constexpr size_t H0_OFF  = 0;                                   // 256*SLOT bf16 = 64 MB
  constexpr size_t H2B_OFF = H0_OFF + (size_t)Tc * SLOT * 2;      // 4*SLOT bf16 = 1 MB
  constexpr size_t F1_OFF  = H2B_OFF + (size_t)4 * SLOT * 2;      // 8 KB
  constexpr size_t F2_OFF  = F1_OFF + 128 * 16 * 4;               // 8 KB

  unsigned short* H0  = (unsigned short*)(ws + H0_OFF);
  unsigned short* h2c = (unsigned short*)(ws + H2B_OFF);
  float* b0s = (float*)(ws + F2_OFF + 128 * 16 * 4);              // 16 KB, after flags
  int* f1 = (int*)(ws + F1_OFF);
  int* f2 = (int*)(ws + F2_OFF);

  // d_out layout during compute (same byte ranges as rounds 8-16; alias proofs carry):
  //   lower half transient: xb (32MB @0) + W0b (4MB @32MB), read only by k_l0.
  //   upper half: h1c [Tc][SLOT] bf16 write-once slots; out[s] (s>=128) overwrites
  //   h1 slots {2s-256, 2s-255} only after the f1/f2 waits order it past all readers.
  unsigned short* xb  = (unsigned short*)d_out;
  unsigned short* W0b = (unsigned short*)d_out + (size_t)Bc * Tc * Ec;
  unsigned short* h1c = (unsigned short*)d_out + (size_t)Tc * SLOT;
  float* out = (float*)d_out;

  int n0 = 4096 * 512;
  k_cvt_bf16<<<n0 / 1024, 256, 0, stream>>>(W_ih0, W0b, n0);
  int nx = Bc * Tc * Ec;
  k_cvt_bf16<<<nx / 1024, 256, 0, stream>>>(x, xb, nx);
  k_prep_small<<<2048, 256, 0, stream>>>(b_ih0, b_hh0, b0s, h2c, f1, f2);
  // new k_l0: grid = (timesteps, j-tiles of 64), 256 threads, 128 KB LDS
  k_l0<<<dim3(Tc, 16), 256, 0, stream>>>(xb, W0b, b0s, H0);

  // PLAIN launch; co-residency structural (~144KB LDS -> 1 WG/CU, grid = 256 = #CUs).
  k_rec<<<dim3(256), dim3(512), 0, stream>>>(H0, W_ihr, W_hhr, b_ihr, b_hhr,
                                             h1c, h2c, f1, f2, out);
}

// Round 18
// 3800.727 us; speedup vs baseline: 1.2828x; 1.0901x over previous
//
#include <hip/hip_runtime.h>

static constexpr int Bc = 128;   // batch
static constexpr int Tc = 256;   // timesteps
static constexpr int Ec = 512;   // input embed
static constexpr int Hc = 1024;  // hidden
static constexpr int SLOT = Bc * Hc;  // one h-state tile (elems)
// chunked h-state layout: [slot][chunk(128)][row(128)][col(8)] bf16
// elem addr (ushorts, within slot) = chunk*1024 + row*8 + col ; chunk = globalcol>>3
// chunk w of any slot is produced by WG w (which owns hidden j = w*8..w*8+7)

using bf16x8 = __attribute__((ext_vector_type(8))) short;
using f32x4  = __attribute__((ext_vector_type(4))) float;

__device__ __forceinline__ unsigned short f2bf(float f) {
  unsigned int u = __float_as_uint(f);
  u += 0x7FFFu + ((u >> 16) & 1u);
  return (unsigned short)(u >> 16);
}
__device__ __forceinline__ float sigm(float x) { return 1.0f / (1.0f + __expf(-x)); }
__device__ __forceinline__ float ftanh(float x) { return 1.0f - 2.0f / (__expf(2.0f * x) + 1.0f); }

#define MFMA16(A, Bf, C) __builtin_amdgcn_mfma_f32_16x16x32_bf16((A), (Bf), (C), 0, 0, 0)

// ---- global sync primitives ----
__device__ __forceinline__ void poll_rlx(const int* p, int tgt) {      // free-path (sleepy)
  while (__hip_atomic_load(p, __ATOMIC_RELAXED, __HIP_MEMORY_SCOPE_AGENT) < tgt)
    __builtin_amdgcn_s_sleep(1);
}
__device__ __forceinline__ void poll_fast(const int* p, int tgt) {     // critical-path
  while (__hip_atomic_load(p, __ATOMIC_RELAXED, __HIP_MEMORY_SCOPE_AGENT) < tgt) {}
}
__device__ __forceinline__ void sig(int* p, int v) {
  __hip_atomic_store(p, v, __ATOMIC_RELAXED, __HIP_MEMORY_SCOPE_AGENT);
}
__device__ __forceinline__ void stg_c(unsigned short* p, unsigned short v) {
  __hip_atomic_store(p, v, __ATOMIC_RELAXED, __HIP_MEMORY_SCOPE_AGENT);
}
// L3-coherent 16B load (bypasses possibly-stale L2) — ONLY for the h2c ring (r16-proven)
__device__ __forceinline__ bf16x8 ldg_c(const unsigned short* p) {
  union { unsigned long long u[2]; bf16x8 v; } r;
  r.u[0] = __hip_atomic_load((const unsigned long long*)p,       __ATOMIC_RELAXED, __HIP_MEMORY_SCOPE_AGENT);
  r.u[1] = __hip_atomic_load((const unsigned long long*)(p + 4), __ATOMIC_RELAXED, __HIP_MEMORY_SCOPE_AGENT);
  return r.v;
}
// ---- LDS (workgroup-scope) flag primitives ----
__device__ __forceinline__ int lds_acq(const int* p) {
  return __hip_atomic_load(p, __ATOMIC_ACQUIRE, __HIP_MEMORY_SCOPE_WORKGROUP);
}
__device__ __forceinline__ void lds_rel(int* p, int v) {
  __hip_atomic_store(p, v, __ATOMIC_RELEASE, __HIP_MEMORY_SCOPE_WORKGROUP);
}

// ----------------- prep kernels (unchanged) -----------------
__global__ void k_cvt_bf16(const float* __restrict__ src, unsigned short* __restrict__ dst, int n) {
  int i = (blockIdx.x * blockDim.x + threadIdx.x) * 4;
  if (i + 3 < n) {
    f32x4 v = *(const f32x4*)(src + i);
    *(ushort4*)(dst + i) = make_ushort4(f2bf(v[0]), f2bf(v[1]), f2bf(v[2]), f2bf(v[3]));
  }
}

__global__ void k_prep_small(const float* __restrict__ bih0, const float* __restrict__ bhh0,
                             float* __restrict__ b0s,
                             unsigned short* __restrict__ h2c,     // [4][SLOT]
                             int* __restrict__ f1, int* __restrict__ f2) {
  int i = blockIdx.x * blockDim.x + threadIdx.x;  // grid covers 4*SLOT = 524288
  if (i < 4096) b0s[i] = bih0[i] + bhh0[i];
  h2c[i] = 0;
  if (i < 128 * 16) { f1[i] = 0; f2[i] = 0; }
}

// ----------------- layer-0 bulk GEMM (r17 traffic-minimal version, unchanged) -----------
__global__ __launch_bounds__(256, 1) void k_l0(
    const unsigned short* __restrict__ xb, const unsigned short* __restrict__ W0,
    const float* __restrict__ b0s, unsigned short* __restrict__ H0)
{
  __shared__ unsigned short Axs[64 * 128 * 8];     // 128 KiB: [chunk(64)][row^swz(128)][8]
  const int tid = threadIdx.x;
  const int lane = tid & 63, wid = tid >> 6;       // 4 waves
  const int bx = blockIdx.x;                       // timestep t
  const int jbase = blockIdx.y * 64 + wid * 16;    // this wave's j-16 slice
  const int ri = lane & 15, kg = lane >> 4;

  for (int i = tid; i < 8192; i += 256) {
    const int row = i >> 6;
    const int chunk = i & 63;
    const int phys = chunk * 128 + (row ^ (chunk & 15));
    *(bf16x8*)(Axs + (size_t)phys * 8) =
        *(const bf16x8*)(xb + ((size_t)row * Tc + bx) * Ec + chunk * 8);
  }
  __syncthreads();

  const int j = jbase + ri;
  const float bi = b0s[j], bg = b0s[2 * Hc + j], bo = b0s[3 * Hc + j];
  const unsigned short* w0r = W0 + ((size_t)(0 * Hc + j)) * Ec + kg * 8;
  const unsigned short* w2r = W0 + ((size_t)(2 * Hc + j)) * Ec + kg * 8;
  const unsigned short* w3r = W0 + ((size_t)(3 * Hc + j)) * Ec + kg * 8;

  f32x4 ai[8], ag[8], ao[8];
#pragma unroll
  for (int u = 0; u < 8; ++u) { ai[u] = (f32x4){0,0,0,0}; ag[u] = (f32x4){0,0,0,0}; ao[u] = (f32x4){0,0,0,0}; }

#pragma unroll 4
  for (int kk = 0; kk < Ec / 32; ++kk) {
    bf16x8 wi = *(const bf16x8*)(w0r + kk * 32);
    bf16x8 wg = *(const bf16x8*)(w2r + kk * 32);
    bf16x8 wo = *(const bf16x8*)(w3r + kk * 32);
    const int ch = kk * 4 + kg;
#pragma unroll
    for (int u = 0; u < 8; ++u) {
      const int phys = ch * 128 + ((u * 16 + ri) ^ (ch & 15));
      bf16x8 a = *(const bf16x8*)(Axs + (size_t)phys * 8);
      ai[u] = MFMA16(a, wi, ai[u]);
      ag[u] = MFMA16(a, wg, ag[u]);
      ao[u] = MFMA16(a, wo, ao[u]);
    }
  }

  unsigned short* hb = H0 + (size_t)bx * SLOT + (size_t)(j >> 3) * 1024 + (j & 7);
#pragma unroll
  for (int u = 0; u < 8; ++u) {
#pragma unroll
    for (int q = 0; q < 4; ++q) {
      const int b = u * 16 + kg * 4 + q;
      float c = sigm(ai[u][q] + bi) * ftanh(ag[u][q] + bg);
      float h = sigm(ao[u][q] + bo) * ftanh(c);
      hb[(size_t)b * 8] = f2bf(h);
    }
  }
}

// ----------------- recurrent kernel: group-pipelined gated consumption ------------------
// 256 WGs x 512 thr (8 waves), 1 WG/CU, PLAIN launch. WGs 0..127: layer1; 128..255:
// layer2. Free waves 0-3: next-step free half -> pbuf (sF/sG LDS stamps), unchanged.
// Gated waves 4-7 NEW: instead of a join over all 128 producers before any compute,
// each wave consumes its gated half in 4 GROUPS of 8 k-steps; group g touches exactly
// chunks/producers 32g..32g+31, so the wave polls those 32 slots (one per lane) just
// before group g. Groups 0-2's polls hit already-set flags; only the last group truly
// waits, overlapped with 3/4 of the gated MM. Layer-2 own-half uses fence-free sc1
// loads (r16-proven); layer-1 gated half uses plain cached loads (write-once slots).
__global__ __launch_bounds__(512, 1) void k_rec(
    const unsigned short* H0,                        // [256][SLOT] chunked (ws)
    const float* __restrict__ Wih, const float* __restrict__ Whh,  // [2][4096][1024] f32
    const float* __restrict__ bih, const float* __restrict__ bhh,  // [2][4096] f32
    unsigned short* h1c,                             // [Tc][SLOT] chunked (d_out upper half)
    unsigned short* h2c,                             // [4][SLOT] chunked (ws)
    int* f1, int* f2,                                // [128] slots x 16 ints (64B stride)
    float* out)                                      // [Tc][Bc][Hc] f32 (d_out)
{
  __shared__ unsigned short Wlds[2 * 64 * 64 * 8];   // 128 KiB: [tile][kstep][lane][8]
  __shared__ float pbuf[4][4][64][4];                // 16 KiB: [m][acc][lane][4] partials
  __shared__ int flg[32];                            // sF[0:4] sG[4:8] (8:12 unused)
                                                     // pollF[12:16] doneS[16:20]
  int* sF_   = flg + 0;
  int* sG_   = flg + 4;
  int* pollF = flg + 12;
  int* doneS = flg + 16;

  const int tid = threadIdx.x;
  const int lane = tid & 63, wid = tid >> 6;         // 8 waves
  const int m = wid & 3;                             // M-pair index within role group
  const bool gatedw = (wid >= 4);
  const int bid = blockIdx.x;
  const int layer = bid >> 7;
  const int w = bid & 127;
  const int j0 = w * 8;
  const int ri = lane & 15, kg = lane >> 4;

  if (tid < 32) flg[tid] = 0;

  // ---- prologue: weights fp32 -> bf16 into LDS, fragment-major (stride 512) ----
  const size_t lw = (size_t)layer * 4096 * 1024;
  for (int s = tid; s < 2 * 64 * 64; s += 512) {
    const int l   = s & 63;
    const int kkg = (s >> 6) & 63;
    const int t   = s >> 12;
    const int rr  = l & 15;
    const int gate = t * 2 + (rr >> 3);
    const int R = gate * 1024 + j0 + (rr & 7);
    const int k = kkg * 32 + (l >> 4) * 8;
    const float* src = (k < 1024) ? (Wih + lw + (size_t)R * 1024 + k)
                                  : (Whh + lw + (size_t)R * 1024 + (k - 1024));
    f32x4 v0 = *(const f32x4*)src;
    f32x4 v1 = *(const f32x4*)(src + 4);
    ushort4* d = (ushort4*)(Wlds + (size_t)s * 8);
    d[0] = make_ushort4(f2bf(v0[0]), f2bf(v0[1]), f2bf(v0[2]), f2bf(v0[3]));
    d[1] = make_ushort4(f2bf(v1[0]), f2bf(v1[1]), f2bf(v1[2]), f2bf(v1[3]));
  }

  const int jme = j0 + (ri & 7);
  const int g0 = (ri < 8) ? 0 : 1;                  // tile0: i | f
  const int g1 = (ri < 8) ? 2 : 3;                  // tile1: g | o
  const float bias0 = bih[layer * 4096 + g0 * 1024 + jme] + bhh[layer * 4096 + g0 * 1024 + jme];
  const float bias1 = bih[layer * 4096 + g1 * 1024 + jme] + bhh[layer * 4096 + g1 * 1024 + jme];

  float c0[4]  = {0.f, 0.f, 0.f, 0.f};              // c-state (gated waves)
  float c1s[4] = {0.f, 0.f, 0.f, 0.f};

  const unsigned short* lds0 = Wlds + (size_t)lane * 8;
  const unsigned short* lds1 = Wlds + (size_t)64 * 64 * 8 + (size_t)lane * 8;
  const int abase = kg * 1024 + (m * 32 + ri) * 8;  // chunked A base (rows m*32+ri, +16)
  const bool lo = (ri < 8);

  f32x4 acc00, acc01, acc10, acc11;
#define ZERO4() { acc00 = (f32x4){0,0,0,0}; acc01 = (f32x4){0,0,0,0}; \
                  acc10 = (f32x4){0,0,0,0}; acc11 = (f32x4){0,0,0,0}; }
#define PLOAD()  { acc00 = *(const f32x4*)&pbuf[m][0][lane][0]; \
                   acc01 = *(const f32x4*)&pbuf[m][1][lane][0]; \
                   acc10 = *(const f32x4*)&pbuf[m][2][lane][0]; \
                   acc11 = *(const f32x4*)&pbuf[m][3][lane][0]; }
#define PWRITE() { *(f32x4*)&pbuf[m][0][lane][0] = acc00; \
                   *(f32x4*)&pbuf[m][1][lane][0] = acc01; \
                   *(f32x4*)&pbuf[m][2][lane][0] = acc10; \
                   *(f32x4*)&pbuf[m][3][lane][0] = acc11; }

// plain cached loads, kk in [K0,K1)
#define HALF_MM4R(Abase, LDSOFF, K0, K1)                                    \
  {                                                                         \
    const unsigned short* ap_ = (Abase) + abase;                            \
    _Pragma("unroll")                                                       \
    for (int kk = (K0); kk < (K1); ++kk) {                                  \
      bf16x8 b0 = *(const bf16x8*)(lds0 + (LDSOFF) + kk * 512);             \
      bf16x8 b1 = *(const bf16x8*)(lds1 + (LDSOFF) + kk * 512);             \
      bf16x8 vlo = *(const bf16x8*)(ap_ + kk * 4096);                       \
      bf16x8 vhi = *(const bf16x8*)(ap_ + kk * 4096 + 128);                 \
      acc00 = MFMA16(vlo, b0, acc00);                                       \
      acc01 = MFMA16(vlo, b1, acc01);                                       \
      acc10 = MFMA16(vhi, b0, acc10);                                       \
      acc11 = MFMA16(vhi, b1, acc11);                                       \
    }                                                                       \
  }

// sc1 L3-coherent loads (h2c ring only), kk in [K0,K1)
#define HALF_MM4C(Abase, LDSOFF, K0, K1)                                    \
  {                                                                         \
    const unsigned short* ap_ = (Abase) + abase;                            \
    _Pragma("unroll")                                                       \
    for (int kk = (K0); kk < (K1); ++kk) {                                  \
      bf16x8 b0 = *(const bf16x8*)(lds0 + (LDSOFF) + kk * 512);             \
      bf16x8 b1 = *(const bf16x8*)(lds1 + (LDSOFF) + kk * 512);             \
      bf16x8 vlo = ldg_c(ap_ + kk * 4096);                                  \
      bf16x8 vhi = ldg_c(ap_ + kk * 4096 + 128);                            \
      acc00 = MFMA16(vlo, b0, acc00);                                       \
      acc01 = MFMA16(vlo, b1, acc01);                                       \
      acc10 = MFMA16(vhi, b0, acc10);                                       \
      acc11 = MFMA16(vhi, b1, acc11);                                       \
    }                                                                       \
  }

#define CELL4(accA, accB, cre, hnarr)                                       \
  _Pragma("unroll")                                                         \
  for (int q = 0; q < 4; ++q) {                                             \
    float x0 = accA[q] + bias0;                                             \
    float x1 = accB[q] + bias1;                                             \
    float p0 = __shfl_xor(x0, 8);                                           \
    float p1 = __shfl_xor(x1, 8);                                           \
    float gi = lo ? x0 : p0;                                                \
    float gf = lo ? p0 : x0;                                                \
    float gg = lo ? x1 : p1;                                                \
    float go = lo ? p1 : x1;                                                \
    float cn = sigm(gf) * cre[q] + sigm(gi) * ftanh(gg);                    \
    hnarr[q] = sigm(go) * ftanh(cn);                                        \
    cre[q] = cn;                                                            \
  }

// free-wave join (sleepy): poll own 32 slots, stamp, spin all four
#define GPOLL_BAR(farr, tgt, stamp)                                         \
  { if (lane < 32) poll_rlx((farr) + (m * 32 + lane) * 16, (tgt));          \
    if (lane == 0) lds_rel(&(stamp)[m], (tgt));                             \
    while (lds_acq(&(stamp)[0]) < (tgt) || lds_acq(&(stamp)[1]) < (tgt) ||  \
           lds_acq(&(stamp)[2]) < (tgt) || lds_acq(&(stamp)[3]) < (tgt)) {} }

  __syncthreads();                                  // Wlds + flags ready (only WG barrier)

  if (layer == 0) {
    if (!gatedw) {
      // ---------- layer-1 FREE wave m: produce partial(t) = H0(t) half ----------
      ZERO4() HALF_MM4R(H0, 0, 0, 32)               // partial(0)
      for (int t = 0; t < Tc; ++t) {
        while (lds_acq(&sG_[m]) < t) {}             // slot free (gated consumed t-1)
        PWRITE()
        if (lane == 0) lds_rel(&sF_[m], t + 1);     // partial(t) published
        if (t + 1 < Tc) { ZERO4() HALF_MM4R(H0 + (size_t)(t + 1) * SLOT, 0, 0, 32) }
      }
    } else {
      // ---------- layer-1 GATED wave m: group-pipelined critical chain ----------
      for (int p = 0; p < Tc; ++p) {
        while (lds_acq(&sF_[m]) < p + 1) {}         // partial(p) ready
        PLOAD()
        if (lane == 0) lds_rel(&sG_[m], p + 1);     // slot consumed
        if (p >= 1) {
          const unsigned short* gb = h1c + (size_t)(p - 1) * SLOT;
          // group g needs exactly producers 32g..32g+31 (chunk = kk*4+kg)
#pragma unroll
          for (int g = 0; g < 4; ++g) {
            if (lane < 32) poll_fast(f1 + (g * 32 + lane) * 16, p);
            HALF_MM4R(gb, 32 * 512, 8 * g, 8 * g + 8)
          }
        }
        float hn0[4], hn1[4];
        CELL4(acc00, acc01, c0, hn0)
        CELL4(acc10, acc11, c1s, hn1)
        if (lo) {
          unsigned short* hb = h1c + (size_t)p * SLOT + (size_t)w * 1024 + (ri & 7);
#pragma unroll
          for (int q = 0; q < 4; ++q) {
            const int r0 = m * 32 + kg * 4 + q;
            stg_c(hb + (size_t)r0 * 8, f2bf(hn0[q]));
            stg_c(hb + (size_t)(r0 + 16) * 8, f2bf(hn1[q]));
          }
        }
        __asm__ volatile("s_waitcnt vmcnt(0)" ::: "memory");  // stores ACKed at L3
        if (lane == 0) lds_rel(&doneS[m], p + 1);
        if (m == 0) {
          while (lds_acq(&doneS[1]) < p + 1 || lds_acq(&doneS[2]) < p + 1 ||
                 lds_acq(&doneS[3]) < p + 1) {}
          if (lane == 0) sig(f1 + w * 16, p + 1);
        }
      }
    }
  } else {
    if (!gatedw) {
      // ---------- layer-2 FREE wave m: produce cross(t) = h1(t) half ----------
      GPOLL_BAR(f1, 1, pollF)                       // h1(0) ready
      ZERO4() HALF_MM4R(h1c, 0, 0, 32)              // cross(0)
      for (int t = 0; t < Tc; ++t) {
        while (lds_acq(&sG_[m]) < t) {}
        PWRITE()
        if (lane == 0) lds_rel(&sF_[m], t + 1);
        if (t + 1 < Tc) {
          GPOLL_BAR(f1, t + 2, pollF)               // h1(t+1) ready everywhere
          ZERO4() HALF_MM4R(h1c + (size_t)(t + 1) * SLOT, 0, 0, 32)
        }
      }
    } else {
      // ---------- layer-2 GATED wave m: group-pipelined critical chain ----------
      for (int s = 0; s < Tc; ++s) {
        while (lds_acq(&sF_[m]) < s + 1) {}         // cross(s) ready
        PLOAD()
        if (lane == 0) lds_rel(&sG_[m], s + 1);
        {
          const unsigned short* gb = h2c + (size_t)((s - 1) & 3) * SLOT;  // s=0: zeros
#pragma unroll
          for (int g = 0; g < 4; ++g) {
            if (s >= 1 && lane < 32) poll_fast(f2 + (g * 32 + lane) * 16, s);
            HALF_MM4C(gb, 32 * 512, 8 * g, 8 * g + 8)
          }
        }
        float hn0[4], hn1[4];
        CELL4(acc00, acc01, c0, hn0)
        CELL4(acc10, acc11, c1s, hn1)
        if (lo) {
          unsigned short* hb = h2c + (size_t)(s & 3) * SLOT + (size_t)w * 1024 + (ri & 7);
#pragma unroll
          for (int q = 0; q < 4; ++q) {
            const int r0 = m * 32 + kg * 4 + q;
            stg_c(hb + (size_t)r0 * 8, f2bf(hn0[q]));
            stg_c(hb + (size_t)(r0 + 16) * 8, f2bf(hn1[q]));
          }
        }
        __asm__ volatile("s_waitcnt vmcnt(0)" ::: "memory");
        if (lane == 0) lds_rel(&doneS[m], s + 1);
        if (m == 0) {
          while (lds_acq(&doneS[1]) < s + 1 || lds_acq(&doneS[2]) < s + 1 ||
                 lds_acq(&doneS[3]) < s + 1) {}
          if (lane == 0) sig(f2 + w * 16, s + 1);
        }
        // out stores off-chain (alias ordering inherited from f1/f2 waits)
        if (lo) {
          float* po = out + (size_t)s * SLOT;
#pragma unroll
          for (int q = 0; q < 4; ++q) {
            const int r0 = m * 32 + kg * 4 + q;
            po[(size_t)r0 * Hc + jme] = hn0[q];
            po[(size_t)(r0 + 16) * Hc + jme] = hn1[q];
          }
        }
      }
    }
  }
}

// ----------------- launcher -----------------
extern "C" void kernel_launch(void* const* d_in, const int* in_sizes, int n_in,
                              void* d_out, int out_size, void* d_ws, size_t ws_size,
                              hipStream_t stream) {
  const float* x     = (const float*)d_in[0];
  const float* W_ih0 = (const float*)d_in[1];
  // d_in[2] = W_hh0 (unused: layer-0 state is always zero)
  const float* b_ih0 = (const float*)d_in[3];
  const float* b_hh0 = (const float*)d_in[4];
  const float* W_ihr = (const float*)d_in[5];
  const float* W_hhr = (const float*)d_in[6];
  const float* b_ihr = (const float*)d_in[7];
  const float* b_hhr = (const float*)d_in[8];

  // ws layout (~65 MB): H0 64MB + h2c 1MB + flags + b0s
  char* ws = (char*)d_ws;
  constexpr size_t H0_OFF  = 0;                                   // 256*SLOT bf16 = 64 MB
  constexpr size_t H2B_OFF = H0_OFF + (size_t)Tc * SLOT * 2;      // 4*SLOT bf16 = 1 MB
  constexpr size_t F1_OFF  = H2B_OFF + (size_t)4 * SLOT * 2;      // 8 KB
  constexpr size_t F2_OFF  = F1_OFF + 128 * 16 * 4;               // 8 KB

  unsigned short* H0  = (unsigned short*)(ws + H0_OFF);
  unsigned short* h2c = (unsigned short*)(ws + H2B_OFF);
  float* b0s = (float*)(ws + F2_OFF + 128 * 16 * 4);              // 16 KB, after flags
  int* f1 = (int*)(ws + F1_OFF);
  int* f2 = (int*)(ws + F2_OFF);

  // d_out layout during compute (same byte ranges as rounds 8-17; alias proofs carry):
  //   lower half transient: xb (32MB @0) + W0b (4MB @32MB), read only by k_l0.
  //   upper half: h1c [Tc][SLOT] bf16 write-once slots; out[s] (s>=128) overwrites
  //   h1 slots {2s-256, 2s-255} only after the f1/f2 waits order it past all readers.
  unsigned short* xb  = (unsigned short*)d_out;
  unsigned short* W0b = (unsigned short*)d_out + (size_t)Bc * Tc * Ec;
  unsigned short* h1c = (unsigned short*)d_out + (size_t)Tc * SLOT;
  float* out = (float*)d_out;

  int n0 = 4096 * 512;
  k_cvt_bf16<<<n0 / 1024, 256, 0, stream>>>(W_ih0, W0b, n0);
  int nx = Bc * Tc * Ec;
  k_cvt_bf16<<<nx / 1024, 256, 0, stream>>>(x, xb, nx);
  k_prep_small<<<2048, 256, 0, stream>>>(b_ih0, b_hh0, b0s, h2c, f1, f2);
  k_l0<<<dim3(Tc, 16), 256, 0, stream>>>(xb, W0b, b0s, H0);

  // PLAIN launch; co-residency structural (~144KB LDS -> 1 WG/CU, grid = 256 = #CUs).
  k_rec<<<dim3(256), dim3(512), 0, stream>>>(H0, W_ihr, W_hhr, b_ihr, b_hhr,
                                             h1c, h2c, f1, f2, out);
}